// Round 6
// baseline (809.401 us; speedup 1.0000x reference)
//
#include <hip/hip_runtime.h>

// ---------------- problem constants ----------------
#define Bb 4
#define Np 4096
#define Ff 6
#define NC 1024
#define NSAMP 64
#define NPTS (Bb*Np)          // 16384 unique points total
// radius^2 exactly as numpy sees it: float32(0.04)
#define R2 ((float)(0.2*0.2))

// ---------------- ws layout (bytes) ----------------
static __host__ __device__ constexpr size_t alup(size_t x){ return (x + 255) & ~(size_t)255; }
static constexpr size_t OFF_GIDX = 0;
static constexpr size_t SZ_GIDX  = (size_t)Bb*NC*NSAMP*4;
static constexpr size_t OFF_MASK = alup(OFF_GIDX + SZ_GIDX);
static constexpr size_t SZ_MASK  = (size_t)Bb*Np*4;
static constexpr size_t OFF_T1   = OFF_MASK + SZ_MASK;        // t1 max  B*256 f32 (plain store by maxmask)
static constexpr size_t OFF_T2   = OFF_T1 + (size_t)Bb*256*4; // t2 max  B*256 f32 (atomic, zero-init)
static constexpr size_t ZERO_BYTES = (OFF_T2 + (size_t)Bb*256*4) - OFF_MASK;
static constexpr size_t OFF_INT  = alup(OFF_T2 + (size_t)Bb*256*4);   // (unused, kept)
static constexpr size_t OFF_FET  = alup(OFF_INT + (size_t)Bb*36*4);   // feT ws B*4096 f32
static constexpr size_t OFF_XT    = alup(OFF_FET + (size_t)Bb*4096*4);      // (unused, kept)
static constexpr size_t OFF_HW    = alup(OFF_XT + (size_t)6*NPTS*4);        // [64][16384]
static constexpr size_t OFF_BUF64 = alup(OFF_HW + (size_t)64*NPTS*4);       // b1/hf  [64][16384]
static constexpr size_t OFF_BUF128= alup(OFF_BUF64 + (size_t)64*NPTS*4);    // b2/c1  [128][16384]
static constexpr size_t OFF_FINAL = alup(OFF_BUF128 + (size_t)128*NPTS*4);  // l3pre (cm) / final (pm) 16MB

// ---------------- DPP helpers ----------------
// full-wave u32 max; result valid in lane 63
__device__ __forceinline__ unsigned wave_red_umax(unsigned v)
{
#define DPP_STEP(ctrl) { unsigned t = (unsigned)__builtin_amdgcn_update_dpp((int)v, (int)v, ctrl, 0xF, 0xF, false); v = (t > v) ? t : v; }
    DPP_STEP(0x111)  // row_shr:1
    DPP_STEP(0x112)  // row_shr:2
    DPP_STEP(0x114)  // row_shr:4
    DPP_STEP(0x118)  // row_shr:8
    DPP_STEP(0x142)  // row_bcast:15
    DPP_STEP(0x143)  // row_bcast:31
#undef DPP_STEP
    return v;
}

// one DPP level of f64 max (positive doubles => u64-order compare)
template<int CTRL>
__device__ __forceinline__ double dpp_max_f64(double v)
{
    int lo = __double2loint(v), hi = __double2hiint(v);
    int tlo = __builtin_amdgcn_update_dpp(lo, lo, CTRL, 0xF, 0xF, false);
    int thi = __builtin_amdgcn_update_dpp(hi, hi, CTRL, 0xF, 0xF, false);
    return fmax(v, __hiloint2double(thi, tlo));
}

// ---------------- MEGA: fps (blocks 0..3) + fused t1 trunk (blocks 4..259) ----------------
// Shared-memory arena manually unioned between the two branches:
//   fps  : sc float4[4096] (64KB) @0, swin double[2][8] @65536           -> 65.7KB
//   trunk: s_in 1.5K @0, s_w1 1.5K @1536, s_a1 16K @3072, s_wst 32K @19456,
//          s_a2 32K @52224                                               -> 83KB
static constexpr int SMEM_BYTES = 84992;

__global__ __launch_bounds__(512) void mega_kernel(const float* __restrict__ points,
                                                   float* __restrict__ out_cent,
                                                   const float* __restrict__ x,
                                                   float* __restrict__ l3pre,
                                                   const float* __restrict__ t1w1,
                                                   const float* __restrict__ t1w2,
                                                   const float* __restrict__ t1w3)
{
    __shared__ __align__(16) char smem[SMEM_BYTES];

    if (blockIdx.x >= Bb) {
        // ---------- fused t1 trunk: 64 points per block, all 3 layers ----------
        int tb = blockIdx.x - Bb;       // 0..255
        int g0 = tb * 64;
        int t  = threadIdx.x;
        float* s_in  = (float*)(smem);            // [6][64]
        float* s_w1  = (float*)(smem + 1536);     // [6][64] (k*64+ch)
        float* s_a1  = (float*)(smem + 3072);     // [64][64]
        float* s_wst = (float*)(smem + 19456);    // 8192 floats: w2 [64][128] then w3 chunk [128][64]
        float* s_a2  = (float*)(smem + 52224);    // [128][64]

        for (int i = t; i < 384; i += 512) {
            int pt = i / 6, c = i % 6;
            s_in[c * 64 + pt] = x[(size_t)(g0 + pt) * 6 + c];
        }
        for (int i = t; i < 384; i += 512)  s_w1[i]  = t1w1[i];
        for (int i = t; i < 8192; i += 512) s_wst[i] = t1w2[i];
        __syncthreads();

        int pt = t & 63;
        // L1: 6 -> 64, relu. 8 ch per thread.
        {
            int c8 = (t >> 6) * 8;
            float a[8];
#pragma unroll
            for (int i = 0; i < 8; ++i) a[i] = 0.f;
#pragma unroll
            for (int k = 0; k < 6; ++k) {
                float av = s_in[k * 64 + pt];
#pragma unroll
                for (int i = 0; i < 8; ++i) a[i] += av * s_w1[k * 64 + c8 + i];
            }
#pragma unroll
            for (int i = 0; i < 8; ++i) s_a1[(c8 + i) * 64 + pt] = fmaxf(a[i], 0.f);
        }
        __syncthreads();
        // L2: 64 -> 128, relu. 16 ch per thread.
        {
            int cg = (t >> 6) * 16;
            float a[16];
#pragma unroll
            for (int i = 0; i < 16; ++i) a[i] = 0.f;
#pragma unroll 4
            for (int k = 0; k < 64; ++k) {
                float av = s_a1[k * 64 + pt];
                const float4* w = (const float4*)&s_wst[k * 128 + cg];
#pragma unroll
                for (int q = 0; q < 4; ++q) {
                    float4 wv = w[q];
                    a[4*q+0] += av * wv.x; a[4*q+1] += av * wv.y;
                    a[4*q+2] += av * wv.z; a[4*q+3] += av * wv.w;
                }
            }
#pragma unroll
            for (int i = 0; i < 16; ++i) s_a2[(cg + i) * 64 + pt] = fmaxf(a[i], 0.f);
        }
        __syncthreads();
        // L3: 128 -> 256, NO relu (maxmask applies it). 4 chunks of 64 ch.
        for (int ch0 = 0; ch0 < 256; ch0 += 64) {
            for (int i = t; i < 8192; i += 512)
                s_wst[i] = t1w3[((size_t)(i >> 6) << 8) + ch0 + (i & 63)];
            __syncthreads();
            int cs = (t >> 6) * 8;
            float a[8];
#pragma unroll
            for (int i = 0; i < 8; ++i) a[i] = 0.f;
#pragma unroll 4
            for (int k = 0; k < 128; ++k) {
                float av = s_a2[k * 64 + pt];
                const float4* w = (const float4*)&s_wst[k * 64 + cs];
                float4 w0 = w[0], w1v = w[1];
                a[0] += av * w0.x;  a[1] += av * w0.y;
                a[2] += av * w0.z;  a[3] += av * w0.w;
                a[4] += av * w1v.x; a[5] += av * w1v.y;
                a[6] += av * w1v.z; a[7] += av * w1v.w;
            }
#pragma unroll
            for (int i = 0; i < 8; ++i)
                l3pre[(size_t)(ch0 + cs + i) * NPTS + g0 + pt] = a[i];
            __syncthreads();
        }
        return;
    }

    // ---------- FPS: 1 block per batch, 512 threads, 8 pts/thread ----------
    int b = blockIdx.x;
    const float* P = points + (size_t)b * Np * 3;
    int tid  = threadIdx.x;
    int lane = tid & 63;
    int wave = tid >> 6;

    float4* sc   = (float4*)(smem);            // [4096] coord table
    double* swin = (double*)(smem + 65536);    // [2][8]

    float px[8], py[8], pz[8], dist[8];
    int ilo[8];
#pragma unroll
    for (int j = 0; j < 8; ++j) {
        int p = tid + (j << 9);
        float xx = P[p*3+0], yy = P[p*3+1], zz = P[p*3+2];
        px[j] = xx; py[j] = yy; pz[j] = zz;
        dist[j] = 1000000000.0f;
        ilo[j] = ~p;
        sc[p] = make_float4(xx, yy, zz, 0.f);
    }
    __syncthreads();

    float cx = sc[0].x, cy = sc[0].y, cz = sc[0].z;
    if (tid == 0) {
        out_cent[((size_t)b*NC + 0)*3 + 0] = cx;
        out_cent[((size_t)b*NC + 0)*3 + 1] = cy;
        out_cent[((size_t)b*NC + 0)*3 + 2] = cz;
    }

    for (int s = 1; s < NC; ++s) {
        double k0 = -1.0, k1 = -1.0, k2 = -1.0, k3 = -1.0;
#pragma unroll
        for (int j = 0; j < 8; ++j) {
            float dx = __fsub_rn(px[j], cx);
            float dy = __fsub_rn(py[j], cy);
            float dz = __fsub_rn(pz[j], cz);
            float d  = __fadd_rn(__fadd_rn(__fmul_rn(dx,dx), __fmul_rn(dy,dy)), __fmul_rn(dz,dz));
            float nd = fminf(dist[j], d);
            dist[j] = nd;
            double kj = __hiloint2double(__float_as_int(nd), ilo[j]);
            if      ((j & 3) == 0) k0 = fmax(k0, kj);
            else if ((j & 3) == 1) k1 = fmax(k1, kj);
            else if ((j & 3) == 2) k2 = fmax(k2, kj);
            else                   k3 = fmax(k3, kj);
        }
        double key = fmax(fmax(k0, k1), fmax(k2, k3));
        key = dpp_max_f64<0x111>(key);
        key = dpp_max_f64<0x112>(key);
        key = dpp_max_f64<0x114>(key);
        key = dpp_max_f64<0x118>(key);
        key = dpp_max_f64<0x142>(key);
        key = dpp_max_f64<0x143>(key);
        if (lane == 63) swin[(s & 1) * 8 + wave] = key;
        __syncthreads();

        const double2* sw = (const double2*)&swin[(s & 1) * 8];
        double2 p01 = sw[0], p23 = sw[1], p45 = sw[2], p67 = sw[3];
        double kk = fmax(fmax(fmax(p01.x, p01.y), fmax(p23.x, p23.y)),
                         fmax(fmax(p45.x, p45.y), fmax(p67.x, p67.y)));
        int widx = ~__double2loint(kk);

        float4 c = sc[widx];
        cx = c.x; cy = c.y; cz = c.z;
        if (tid == 0) {
            out_cent[((size_t)b*NC + s)*3 + 0] = cx;
            out_cent[((size_t)b*NC + s)*3 + 1] = cy;
            out_cent[((size_t)b*NC + s)*3 + 2] = cz;
        }
    }
}

// ---------------- ball query + g_xyz + mask ----------------
__global__ __launch_bounds__(256) void ballq_kernel(const float* __restrict__ points,
                                                    const float* __restrict__ cent,
                                                    int* __restrict__ gidx,
                                                    int* __restrict__ mask,
                                                    float* __restrict__ out_gxyz)
{
    int gtid = blockIdx.x * 256 + threadIdx.x;
    int wid  = gtid >> 6;          // b*1024 + c
    int lane = threadIdx.x & 63;
    int b = wid >> 10, c = wid & 1023;
    const float* P = points + (size_t)b * Np * 3;
    float cx = cent[((size_t)b*NC + c)*3 + 0];
    float cy = cent[((size_t)b*NC + c)*3 + 1];
    float cz = cent[((size_t)b*NC + c)*3 + 2];

    __shared__ int sidx[4][NSAMP];
    int* my = sidx[threadIdx.x >> 6];

    int count = 0;
    for (int base = 0; base < Np; base += 64) {
        int p = base + lane;
        float dx = __fsub_rn(cx, P[p*3+0]);
        float dy = __fsub_rn(cy, P[p*3+1]);
        float dz = __fsub_rn(cz, P[p*3+2]);
        float d  = __fadd_rn(__fadd_rn(__fmul_rn(dx,dx), __fmul_rn(dy,dy)), __fmul_rn(dz,dz));
        bool inr = !(d > R2);
        unsigned long long mball = __ballot(inr);
        int before = __popcll(mball & ((1ull << lane) - 1ull));
        int pos = count + before;
        if (inr && pos < NSAMP) my[pos] = p;
        count += (int)__popcll(mball);
        if (count >= NSAMP) break;
    }
    __syncthreads();
    int total = count < NSAMP ? count : NSAMP;
    int first = my[0];
    int myi = (lane < total) ? my[lane] : first;
    gidx[(size_t)wid * NSAMP + lane] = myi;
    mask[(size_t)b * Np + myi] = 1;
    float qx = P[myi*3+0], qy = P[myi*3+1], qz = P[myi*3+2];
    out_gxyz[(((size_t)b*3 + 0)*NC + c)*NSAMP + lane] = __fsub_rn(qx, cx);
    out_gxyz[(((size_t)b*3 + 1)*NC + c)*NSAMP + lane] = __fsub_rn(qy, cy);
    out_gxyz[(((size_t)b*3 + 2)*NC + c)*NSAMP + lane] = __fsub_rn(qz, cz);
}

// ---------------- masked per-(b,ch) relu-max over points ----------------
// buf: [256][16384] channel-major. grid = Bb*256 blocks of 256 threads.
__global__ __launch_bounds__(256) void maxmask_kernel(const float* __restrict__ buf,
                                                      const int* __restrict__ mask,
                                                      float* __restrict__ tmax)
{
    int bid = blockIdx.x;
    int b = bid >> 8, ch = bid & 255;
    int tid = threadIdx.x;
    const float* row = buf + (size_t)ch * NPTS + (size_t)b * Np;
    const int* mk = mask + (size_t)b * Np;
    float m = 0.f;
#pragma unroll
    for (int i = 0; i < Np / 256; ++i) {
        int p = tid + i * 256;
        float v = row[p];
        if (mk[p]) m = fmaxf(m, fmaxf(v, 0.f));
    }
#pragma unroll
    for (int off = 1; off < 64; off <<= 1)
        m = fmaxf(m, __shfl_xor(m, off));
    __shared__ float red[4];
    if ((tid & 63) == 0) red[tid >> 6] = m;
    __syncthreads();
    if (tid == 0) {
        float r = fmaxf(fmaxf(red[0], red[1]), fmaxf(red[2], red[3]));
        tmax[(size_t)b * 256 + ch] = r;
    }
}

// ---------------- register-blocked layer: out = [relu](in @ W) ----------------
template<int K, int N, int NT, bool RELU, bool PM, bool BW, bool TM>
__global__ __launch_bounds__(256) void layer2_k(const float* __restrict__ in,
                                                const float* __restrict__ W,
                                                float* __restrict__ out,
                                                const int* __restrict__ mask,
                                                unsigned* __restrict__ tmax)
{
    static_assert(NT % 4 == 0, "NT multiple of 4");
    int tid = threadIdx.x;
    int g0  = blockIdx.x * 1024 + tid;
    int o0  = blockIdx.y * NT;
    const float* Wb = W;
    if (BW) Wb += (size_t)(blockIdx.x >> 2) * K * N;

    __shared__ __align__(16) float ws[K * NT];
    for (int i = tid; i < K * NT; i += 256)
        ws[i] = Wb[(size_t)(i / NT) * N + o0 + (i % NT)];
    __syncthreads();

    float acc[4][NT];
#pragma unroll
    for (int mi = 0; mi < 4; ++mi)
#pragma unroll
        for (int oo = 0; oo < NT; ++oo) acc[mi][oo] = 0.f;

#pragma unroll 2
    for (int k = 0; k < K; ++k) {
        float a0 = in[(size_t)k * NPTS + g0];
        float a1 = in[(size_t)k * NPTS + g0 + 256];
        float a2 = in[(size_t)k * NPTS + g0 + 512];
        float a3 = in[(size_t)k * NPTS + g0 + 768];
        const float4* wr = (const float4*)&ws[k * NT];
#pragma unroll
        for (int q = 0; q < NT/4; ++q) {
            float4 w = wr[q];
            acc[0][4*q+0] += a0 * w.x;  acc[0][4*q+1] += a0 * w.y;
            acc[0][4*q+2] += a0 * w.z;  acc[0][4*q+3] += a0 * w.w;
            acc[1][4*q+0] += a1 * w.x;  acc[1][4*q+1] += a1 * w.y;
            acc[1][4*q+2] += a1 * w.z;  acc[1][4*q+3] += a1 * w.w;
            acc[2][4*q+0] += a2 * w.x;  acc[2][4*q+1] += a2 * w.y;
            acc[2][4*q+2] += a2 * w.z;  acc[2][4*q+3] += a2 * w.w;
            acc[3][4*q+0] += a3 * w.x;  acc[3][4*q+1] += a3 * w.y;
            acc[3][4*q+2] += a3 * w.z;  acc[3][4*q+3] += a3 * w.w;
        }
    }

    if (TM) {
        float tmv[NT];
#pragma unroll
        for (int oo = 0; oo < NT; ++oo) tmv[oo] = 0.f;
#pragma unroll
        for (int mi = 0; mi < 4; ++mi) {
            bool pres = mask[g0 + mi * 256] != 0;
#pragma unroll
            for (int oo = 0; oo < NT; ++oo) {
                float v = pres ? fmaxf(acc[mi][oo], 0.f) : 0.f;
                tmv[oo] = fmaxf(tmv[oo], v);
            }
        }
        int b = g0 >> 12;
        int lane = tid & 63;
#pragma unroll
        for (int oo = 0; oo < NT; ++oo) {
            unsigned r = wave_red_umax(__float_as_uint(tmv[oo]));
            if (lane == 63)
                atomicMax(&tmax[(b << 8) + o0 + oo], r);
        }
        return;
    }

#pragma unroll
    for (int mi = 0; mi < 4; ++mi) {
        int g = g0 + mi * 256;
#pragma unroll
        for (int oo = 0; oo < NT; ++oo) {
            float v = acc[mi][oo];
            if (RELU) v = fmaxf(v, 0.f);
            if (PM) out[(size_t)g * N + o0 + oo] = v;
            else    out[(size_t)(o0 + oo) * NPTS + g] = v;
        }
    }
}

// ---------------- h = relu((x @ inT) @ w1), head1 fused as prologue ----------------
// grid = 64 blocks x 256 thr; block covers 256 pts (16 blocks per batch).
__global__ __launch_bounds__(256) void l_h_kernel(const float* __restrict__ x,
                                                  const float* __restrict__ t1max,
                                                  const float* __restrict__ f1,   // 256x128
                                                  const float* __restrict__ f2,   // 128x36
                                                  const float* __restrict__ w1,   // 6x64
                                                  float* __restrict__ out_inT,    // (4,6,6)
                                                  float* __restrict__ hw)
{
    int blk = blockIdx.x, t = threadIdx.x;
    int b = blk >> 4;
    __shared__ float tv[256], u[128], sT[36];
    tv[t] = t1max[(size_t)b*256 + t];
    __syncthreads();
    if (t < 128) {
        float acc = 0.f;
        for (int k = 0; k < 256; ++k) acc += tv[k] * f1[(size_t)k*128 + t];
        u[t] = fmaxf(acc, 0.f);
    }
    __syncthreads();
    if (t < 36) {
        float acc = 0.f;
        for (int k = 0; k < 128; ++k) acc += u[k] * f2[(size_t)k*36 + t];
        if (t / 6 == t % 6) acc += 1.0f;
        sT[t] = acc;
        if ((blk & 15) == 0) out_inT[b*36 + t] = acc;
    }
    __syncthreads();

    int g = blk * 256 + t;
    float v[6];
#pragma unroll
    for (int c = 0; c < 6; ++c) v[c] = x[(size_t)g * 6 + c];
    float tt[6];
#pragma unroll
    for (int o = 0; o < 6; ++o) {
        float acc = 0.f;
#pragma unroll
        for (int c = 0; c < 6; ++c) acc += v[c] * sT[c*6 + o];
        tt[o] = acc;
    }
#pragma unroll 8
    for (int j = 0; j < 64; ++j) {
        float acc = 0.f;
#pragma unroll
        for (int o = 0; o < 6; ++o) acc += tt[o] * w1[o*64 + j];
        hw[(size_t)j * NPTS + g] = fmaxf(acc, 0.f);
    }
}

// ---------------- tnet2 head ----------------
__global__ __launch_bounds__(256) void head2_kernel(const float* __restrict__ t2,
                                                    const float* __restrict__ f1,  // 256x128
                                                    const float* __restrict__ f2,  // 128x4096
                                                    float* __restrict__ outT, float* __restrict__ wsT)
{
    int b = blockIdx.x, t = threadIdx.x;
    __shared__ float tv[256], u[128];
    tv[t] = t2[(size_t)b*256 + t];
    __syncthreads();
    if (t < 128) {
        float acc = 0.f;
        for (int k = 0; k < 256; ++k) acc += tv[k] * f1[(size_t)k*128 + t];
        u[t] = fmaxf(acc, 0.f);
    }
    __syncthreads();
    int j = blockIdx.y * 256 + t;
    float acc = 0.f;
#pragma unroll 8
    for (int k = 0; k < 128; ++k) acc += u[k] * f2[(size_t)k*4096 + j];
    if (j / 64 == j % 64) acc += 1.0f;
    outT[(size_t)b*4096 + j] = acc;
    wsT[(size_t)b*4096 + j]  = acc;
}

// ---------------- feats: grouped gather-max + transpose ----------------
__global__ __launch_bounds__(256) void feats_kernel(const float* __restrict__ fin,   // [16384][256] pm
                                                    const int* __restrict__ gidx,
                                                    float* __restrict__ out)         // (B,256,1024)
{
    int bid = blockIdx.x;            // b*1024 + c
    int b = bid >> 10, c = bid & 1023;
    int o = threadIdx.x;
    __shared__ int sid[NSAMP];
    if (o < NSAMP) sid[o] = gidx[(size_t)bid * NSAMP + o];
    __syncthreads();
    const float* fb = fin + (size_t)b * Np * 256;
    float m = -1e30f;
    for (int s = 0; s < NSAMP; ++s)
        m = fmaxf(m, fb[(size_t)sid[s] * 256 + o]);
    out[((size_t)b*256 + o)*NC + c] = m;
}

// ---------------- launch ----------------
extern "C" void kernel_launch(void* const* d_in, const int* in_sizes, int n_in,
                              void* d_out, int out_size, void* d_ws, size_t ws_size,
                              hipStream_t stream)
{
    const float* x      = (const float*)d_in[0];
    const float* points = (const float*)d_in[1];
    const float* t1_w1  = (const float*)d_in[2];
    const float* t1_w2  = (const float*)d_in[3];
    const float* t1_w3  = (const float*)d_in[4];
    const float* t1_f1  = (const float*)d_in[5];
    const float* t1_f2  = (const float*)d_in[6];
    const float* t2_w1  = (const float*)d_in[7];
    const float* t2_w2  = (const float*)d_in[8];
    const float* t2_w3  = (const float*)d_in[9];
    const float* t2_f1  = (const float*)d_in[10];
    const float* t2_f2  = (const float*)d_in[11];
    const float* w1     = (const float*)d_in[12];
    const float* w2     = (const float*)d_in[13];
    const float* w3     = (const float*)d_in[14];

    float* out = (float*)d_out;
    float* out_cent  = out;                 // (4,1024,3)
    float* out_gxyz  = out + 12288;         // (4,3,1024,64)
    float* out_feats = out + 798720;        // (4,256,1024)
    float* out_inT   = out + 1847296;       // (4,6,6)
    float* out_feT   = out + 1847440;       // (4,64,64)

    char* ws = (char*)d_ws;
    int*      gidx  = (int*)(ws + OFF_GIDX);
    int*      mask  = (int*)(ws + OFF_MASK);
    float*    t1max = (float*)(ws + OFF_T1);
    unsigned* t2max = (unsigned*)(ws + OFF_T2);
    float*    wsFeT = (float*)(ws + OFF_FET);
    float*    hw    = (float*)(ws + OFF_HW);
    float*    buf64 = (float*)(ws + OFF_BUF64);
    float*    buf128= (float*)(ws + OFF_BUF128);
    float*    fin   = (float*)(ws + OFF_FINAL);   // l3pre (cm) then final (pm)

    // zero mask + t1max + t2max (contiguous)
    (void)hipMemsetAsync(ws + OFF_MASK, 0, ZERO_BYTES, stream);

    // mega: fps (4 blocks) + fused t1 trunk (256 blocks) -> l3pre
    mega_kernel<<<Bb + 256, 512, 0, stream>>>(points, out_cent, x, fin, t1_w1, t1_w2, t1_w3);
    ballq_kernel<<<(Bb*NC)/4, 256, 0, stream>>>(points, out_cent, gidx, mask, out_gxyz);
    // t1 masked max (reads l3pre channel-major)
    maxmask_kernel<<<Bb*256, 256, 0, stream>>>(fin, mask, t1max);
    // h = relu((x @ inT) @ w1), head1 fused
    l_h_kernel<<<NPTS/256, 256, 0, stream>>>(x, t1max, t1_f1, t1_f2, w1, out_inT, hw);
    // tnet2 trunk (layer3 fused with masked max)
    layer2_k<64, 64, 16, true,  false, false, false><<<dim3(16, 4), 256, 0, stream>>>(hw,    t2_w1, buf64,  nullptr, nullptr);
    layer2_k<64, 128,16, true,  false, false, false><<<dim3(16, 8), 256, 0, stream>>>(buf64, t2_w2, buf128, nullptr, nullptr);
    layer2_k<128,256,16, false, false, false, true ><<<dim3(16,16), 256, 0, stream>>>(buf128,t2_w3, nullptr, mask, t2max);
    head2_kernel<<<dim3(Bb,16), 256, 0, stream>>>((const float*)t2max, t2_f1, t2_f2, out_feT, wsFeT);
    // hf = h @ feT (per-batch weights)
    layer2_k<64, 64, 16, false, false, true,  false><<<dim3(16, 4), 256, 0, stream>>>(hw,    wsFeT, buf64,  nullptr, nullptr);
    // c1 = relu(hf @ w2)
    layer2_k<64, 128,16, true,  false, false, false><<<dim3(16, 8), 256, 0, stream>>>(buf64, w2,    buf128, nullptr, nullptr);
    // final = relu(c1 @ w3), point-major
    layer2_k<128,256,16, true,  true,  false, false><<<dim3(16,16), 256, 0, stream>>>(buf128,w3,    fin,    nullptr, nullptr);
    feats_kernel<<<Bb*NC, 256, 0, stream>>>(fin, gidx, out_feats);

    (void)in_sizes; (void)n_in; (void)out_size; (void)ws_size;
}

// Round 7
// 758.906 us; speedup vs baseline: 1.0665x; 1.0665x over previous
//
#include <hip/hip_runtime.h>

// ---------------- problem constants ----------------
#define Bb 4
#define Np 4096
#define Ff 6
#define NC 1024
#define NSAMP 64
#define NPTS (Bb*Np)          // 16384 unique points total
// radius^2 exactly as numpy sees it: float32(0.04)
#define R2 ((float)(0.2*0.2))

// ---------------- ws layout (bytes) ----------------
static __host__ __device__ constexpr size_t alup(size_t x){ return (x + 255) & ~(size_t)255; }
static constexpr size_t OFF_GIDX = 0;
static constexpr size_t SZ_GIDX  = (size_t)Bb*NC*NSAMP*4;
static constexpr size_t OFF_MASK = alup(OFF_GIDX + SZ_GIDX);
static constexpr size_t SZ_MASK  = (size_t)Bb*Np*4;
static constexpr size_t OFF_T1   = OFF_MASK + SZ_MASK;        // t1 max  B*256 f32 (plain store by maxmask)
static constexpr size_t OFF_T2   = OFF_T1 + (size_t)Bb*256*4; // t2 max  B*256 f32 (atomic, zero-init)
static constexpr size_t ZERO_BYTES = (OFF_T2 + (size_t)Bb*256*4) - OFF_MASK;
static constexpr size_t OFF_INT  = alup(OFF_T2 + (size_t)Bb*256*4);   // (unused, kept)
static constexpr size_t OFF_FET  = alup(OFF_INT + (size_t)Bb*36*4);   // feT ws B*4096 f32
static constexpr size_t OFF_XT    = alup(OFF_FET + (size_t)Bb*4096*4);      // (unused, kept)
static constexpr size_t OFF_HW    = alup(OFF_XT + (size_t)6*NPTS*4);        // [64][16384]
static constexpr size_t OFF_BUF64 = alup(OFF_HW + (size_t)64*NPTS*4);       // b1/hf  [64][16384]
static constexpr size_t OFF_BUF128= alup(OFF_BUF64 + (size_t)64*NPTS*4);    // b2/c1  [128][16384]
static constexpr size_t OFF_FINAL = alup(OFF_BUF128 + (size_t)128*NPTS*4);  // l3pre (cm) / final (pm) 16MB

// ---------------- DPP helpers ----------------
// full-wave u32 max; result valid in lane 63
__device__ __forceinline__ unsigned wave_red_umax(unsigned v)
{
#define DPP_STEP(ctrl) { unsigned t = (unsigned)__builtin_amdgcn_update_dpp((int)v, (int)v, ctrl, 0xF, 0xF, false); v = (t > v) ? t : v; }
    DPP_STEP(0x111)  // row_shr:1
    DPP_STEP(0x112)  // row_shr:2
    DPP_STEP(0x114)  // row_shr:4
    DPP_STEP(0x118)  // row_shr:8
    DPP_STEP(0x142)  // row_bcast:15
    DPP_STEP(0x143)  // row_bcast:31
#undef DPP_STEP
    return v;
}

// one DPP level of f64 max (positive doubles => u64-order compare)
template<int CTRL>
__device__ __forceinline__ double dpp_max_f64(double v)
{
    int lo = __double2loint(v), hi = __double2hiint(v);
    int tlo = __builtin_amdgcn_update_dpp(lo, lo, CTRL, 0xF, 0xF, false);
    int thi = __builtin_amdgcn_update_dpp(hi, hi, CTRL, 0xF, 0xF, false);
    return fmax(v, __hiloint2double(thi, tlo));
}

// ---------------- MEGA: fps (blocks 0..3) + fused t1 trunk (blocks 4..259) ----------------
// 256 threads everywhere. Shared arena unioned:
//   fps  : sc float4[4096] (64KB) @0, swin double[2][4] @65536           -> 65.6KB
//   trunk: s_in 1.5K @0, s_w1 1.5K @1536, s_a1 16K @3072, s_wst 32K @19456,
//          s_a2 32K @52224                                               -> 83KB
static constexpr int SMEM_BYTES = 84992;

__global__ __launch_bounds__(256) void mega_kernel(const float* __restrict__ points,
                                                   float* __restrict__ out_cent,
                                                   const float* __restrict__ x,
                                                   float* __restrict__ l3pre,
                                                   const float* __restrict__ t1w1,
                                                   const float* __restrict__ t1w2,
                                                   const float* __restrict__ t1w3)
{
    __shared__ __align__(16) char smem[SMEM_BYTES];

    if (blockIdx.x >= Bb) {
        // ---------- fused t1 trunk: 64 points per block, all 3 layers, 256 thr ----------
        int tb = blockIdx.x - Bb;       // 0..255
        int g0 = tb * 64;
        int t  = threadIdx.x;
        float* s_in  = (float*)(smem);            // [6][64]
        float* s_w1  = (float*)(smem + 1536);     // [6][64] (k*64+ch)
        float* s_a1  = (float*)(smem + 3072);     // [64][64]
        float* s_wst = (float*)(smem + 19456);    // 8192 floats: w2 [64][128] then w3 chunk [128][64]
        float* s_a2  = (float*)(smem + 52224);    // [128][64]

        for (int i = t; i < 384; i += 256) {
            int pt = i / 6, c = i % 6;
            s_in[c * 64 + pt] = x[(size_t)(g0 + pt) * 6 + c];
        }
        for (int i = t; i < 384; i += 256)  s_w1[i]  = t1w1[i];
        for (int i = t; i < 8192; i += 256) s_wst[i] = t1w2[i];
        __syncthreads();

        int pt = t & 63;
        int grp = t >> 6;          // 0..3
        // L1: 6 -> 64, relu. 16 ch per thread.
        {
            int c0 = grp * 16;
            float a[16];
#pragma unroll
            for (int i = 0; i < 16; ++i) a[i] = 0.f;
#pragma unroll
            for (int k = 0; k < 6; ++k) {
                float av = s_in[k * 64 + pt];
#pragma unroll
                for (int i = 0; i < 16; ++i) a[i] += av * s_w1[k * 64 + c0 + i];
            }
#pragma unroll
            for (int i = 0; i < 16; ++i) s_a1[(c0 + i) * 64 + pt] = fmaxf(a[i], 0.f);
        }
        __syncthreads();
        // L2: 64 -> 128, relu. 32 ch per thread.
        {
            int cg = grp * 32;
            float a[32];
#pragma unroll
            for (int i = 0; i < 32; ++i) a[i] = 0.f;
#pragma unroll 2
            for (int k = 0; k < 64; ++k) {
                float av = s_a1[k * 64 + pt];
                const float4* w = (const float4*)&s_wst[k * 128 + cg];
#pragma unroll
                for (int q = 0; q < 8; ++q) {
                    float4 wv = w[q];
                    a[4*q+0] += av * wv.x; a[4*q+1] += av * wv.y;
                    a[4*q+2] += av * wv.z; a[4*q+3] += av * wv.w;
                }
            }
#pragma unroll
            for (int i = 0; i < 32; ++i) s_a2[(cg + i) * 64 + pt] = fmaxf(a[i], 0.f);
        }
        __syncthreads();
        // L3: 128 -> 256, NO relu (maxmask applies it). 4 chunks of 64 ch; 16 ch/thread.
        for (int ch0 = 0; ch0 < 256; ch0 += 64) {
            for (int i = t; i < 8192; i += 256)
                s_wst[i] = t1w3[((size_t)(i >> 6) << 8) + ch0 + (i & 63)];
            __syncthreads();
            int cs = grp * 16;
            float a[16];
#pragma unroll
            for (int i = 0; i < 16; ++i) a[i] = 0.f;
#pragma unroll 2
            for (int k = 0; k < 128; ++k) {
                float av = s_a2[k * 64 + pt];
                const float4* w = (const float4*)&s_wst[k * 64 + cs];
#pragma unroll
                for (int q = 0; q < 4; ++q) {
                    float4 wv = w[q];
                    a[4*q+0] += av * wv.x; a[4*q+1] += av * wv.y;
                    a[4*q+2] += av * wv.z; a[4*q+3] += av * wv.w;
                }
            }
#pragma unroll
            for (int i = 0; i < 16; ++i)
                l3pre[(size_t)(ch0 + cs + i) * NPTS + g0 + pt] = a[i];
            __syncthreads();
        }
        return;
    }

    // ---------- FPS: 1 block per batch, 256 threads, 16 pts/thread ----------
    // dist kept AS the f64 key: hi reg = dist bits (f32), lo reg = ~idx (constant).
    int b = blockIdx.x;
    const float* P = points + (size_t)b * Np * 3;
    int tid  = threadIdx.x;
    int lane = tid & 63;
    int wave = tid >> 6;

    float4* sc   = (float4*)(smem);            // [4096] coord table
    double* swin = (double*)(smem + 65536);    // [2][4]

    float px[16], py[16], pz[16];
    double dk[16];
#pragma unroll
    for (int j = 0; j < 16; ++j) {
        int p = tid + (j << 8);
        float xx = P[p*3+0], yy = P[p*3+1], zz = P[p*3+2];
        px[j] = xx; py[j] = yy; pz[j] = zz;
        dk[j] = __hiloint2double(__float_as_int(1000000000.0f), ~p);
        sc[p] = make_float4(xx, yy, zz, 0.f);
    }
    __syncthreads();

    float cx = sc[0].x, cy = sc[0].y, cz = sc[0].z;
    if (tid == 0) {
        out_cent[((size_t)b*NC + 0)*3 + 0] = cx;
        out_cent[((size_t)b*NC + 0)*3 + 1] = cy;
        out_cent[((size_t)b*NC + 0)*3 + 2] = cz;
    }

    for (int s = 1; s < NC; ++s) {
        double k0 = -1.0, k1 = -1.0, k2 = -1.0, k3 = -1.0;
#pragma unroll
        for (int j = 0; j < 16; ++j) {
            float dx = __fsub_rn(px[j], cx);
            float dy = __fsub_rn(py[j], cy);
            float dz = __fsub_rn(pz[j], cz);
            float d  = __fadd_rn(__fadd_rn(__fmul_rn(dx,dx), __fmul_rn(dy,dy)), __fmul_rn(dz,dz));
            float cur = __uint_as_float((unsigned)__double2hiint(dk[j]));
            float nd  = fminf(cur, d);
            dk[j] = __hiloint2double(__float_as_int(nd), __double2loint(dk[j]));
            if      ((j & 3) == 0) k0 = fmax(k0, dk[j]);
            else if ((j & 3) == 1) k1 = fmax(k1, dk[j]);
            else if ((j & 3) == 2) k2 = fmax(k2, dk[j]);
            else                   k3 = fmax(k3, dk[j]);
        }
        double key = fmax(fmax(k0, k1), fmax(k2, k3));
        key = dpp_max_f64<0x111>(key);
        key = dpp_max_f64<0x112>(key);
        key = dpp_max_f64<0x114>(key);
        key = dpp_max_f64<0x118>(key);
        key = dpp_max_f64<0x142>(key);
        key = dpp_max_f64<0x143>(key);
        if (lane == 63) swin[(s & 1) * 4 + wave] = key;
        __syncthreads();

        const double2* sw = (const double2*)&swin[(s & 1) * 4];
        double2 p01 = sw[0], p23 = sw[1];
        double kk = fmax(fmax(p01.x, p01.y), fmax(p23.x, p23.y));
        int widx = ~__double2loint(kk);

        float4 c = sc[widx];
        cx = c.x; cy = c.y; cz = c.z;
        if (tid == 0) {
            out_cent[((size_t)b*NC + s)*3 + 0] = cx;
            out_cent[((size_t)b*NC + s)*3 + 1] = cy;
            out_cent[((size_t)b*NC + s)*3 + 2] = cz;
        }
    }
}

// ---------------- ball query + g_xyz + mask ----------------
__global__ __launch_bounds__(256) void ballq_kernel(const float* __restrict__ points,
                                                    const float* __restrict__ cent,
                                                    int* __restrict__ gidx,
                                                    int* __restrict__ mask,
                                                    float* __restrict__ out_gxyz)
{
    int gtid = blockIdx.x * 256 + threadIdx.x;
    int wid  = gtid >> 6;          // b*1024 + c
    int lane = threadIdx.x & 63;
    int b = wid >> 10, c = wid & 1023;
    const float* P = points + (size_t)b * Np * 3;
    float cx = cent[((size_t)b*NC + c)*3 + 0];
    float cy = cent[((size_t)b*NC + c)*3 + 1];
    float cz = cent[((size_t)b*NC + c)*3 + 2];

    __shared__ int sidx[4][NSAMP];
    int* my = sidx[threadIdx.x >> 6];

    int count = 0;
    for (int base = 0; base < Np; base += 64) {
        int p = base + lane;
        float dx = __fsub_rn(cx, P[p*3+0]);
        float dy = __fsub_rn(cy, P[p*3+1]);
        float dz = __fsub_rn(cz, P[p*3+2]);
        float d  = __fadd_rn(__fadd_rn(__fmul_rn(dx,dx), __fmul_rn(dy,dy)), __fmul_rn(dz,dz));
        bool inr = !(d > R2);
        unsigned long long mball = __ballot(inr);
        int before = __popcll(mball & ((1ull << lane) - 1ull));
        int pos = count + before;
        if (inr && pos < NSAMP) my[pos] = p;
        count += (int)__popcll(mball);
        if (count >= NSAMP) break;
    }
    __syncthreads();
    int total = count < NSAMP ? count : NSAMP;
    int first = my[0];
    int myi = (lane < total) ? my[lane] : first;
    gidx[(size_t)wid * NSAMP + lane] = myi;
    mask[(size_t)b * Np + myi] = 1;
    float qx = P[myi*3+0], qy = P[myi*3+1], qz = P[myi*3+2];
    out_gxyz[(((size_t)b*3 + 0)*NC + c)*NSAMP + lane] = __fsub_rn(qx, cx);
    out_gxyz[(((size_t)b*3 + 1)*NC + c)*NSAMP + lane] = __fsub_rn(qy, cy);
    out_gxyz[(((size_t)b*3 + 2)*NC + c)*NSAMP + lane] = __fsub_rn(qz, cz);
}

// ---------------- masked per-(b,ch) relu-max over points ----------------
__global__ __launch_bounds__(256) void maxmask_kernel(const float* __restrict__ buf,
                                                      const int* __restrict__ mask,
                                                      float* __restrict__ tmax)
{
    int bid = blockIdx.x;
    int b = bid >> 8, ch = bid & 255;
    int tid = threadIdx.x;
    const float* row = buf + (size_t)ch * NPTS + (size_t)b * Np;
    const int* mk = mask + (size_t)b * Np;
    float m = 0.f;
#pragma unroll
    for (int i = 0; i < Np / 256; ++i) {
        int p = tid + i * 256;
        float v = row[p];
        if (mk[p]) m = fmaxf(m, fmaxf(v, 0.f));
    }
#pragma unroll
    for (int off = 1; off < 64; off <<= 1)
        m = fmaxf(m, __shfl_xor(m, off));
    __shared__ float red[4];
    if ((tid & 63) == 0) red[tid >> 6] = m;
    __syncthreads();
    if (tid == 0) {
        float r = fmaxf(fmaxf(red[0], red[1]), fmaxf(red[2], red[3]));
        tmax[(size_t)b * 256 + ch] = r;
    }
}

// ---------------- register-blocked layer: out = [relu](in @ W) ----------------
template<int K, int N, int NT, bool RELU, bool PM, bool BW, bool TM>
__global__ __launch_bounds__(256) void layer2_k(const float* __restrict__ in,
                                                const float* __restrict__ W,
                                                float* __restrict__ out,
                                                const int* __restrict__ mask,
                                                unsigned* __restrict__ tmax)
{
    static_assert(NT % 4 == 0, "NT multiple of 4");
    int tid = threadIdx.x;
    int g0  = blockIdx.x * 1024 + tid;
    int o0  = blockIdx.y * NT;
    const float* Wb = W;
    if (BW) Wb += (size_t)(blockIdx.x >> 2) * K * N;

    __shared__ __align__(16) float ws[K * NT];
    for (int i = tid; i < K * NT; i += 256)
        ws[i] = Wb[(size_t)(i / NT) * N + o0 + (i % NT)];
    __syncthreads();

    float acc[4][NT];
#pragma unroll
    for (int mi = 0; mi < 4; ++mi)
#pragma unroll
        for (int oo = 0; oo < NT; ++oo) acc[mi][oo] = 0.f;

#pragma unroll 2
    for (int k = 0; k < K; ++k) {
        float a0 = in[(size_t)k * NPTS + g0];
        float a1 = in[(size_t)k * NPTS + g0 + 256];
        float a2 = in[(size_t)k * NPTS + g0 + 512];
        float a3 = in[(size_t)k * NPTS + g0 + 768];
        const float4* wr = (const float4*)&ws[k * NT];
#pragma unroll
        for (int q = 0; q < NT/4; ++q) {
            float4 w = wr[q];
            acc[0][4*q+0] += a0 * w.x;  acc[0][4*q+1] += a0 * w.y;
            acc[0][4*q+2] += a0 * w.z;  acc[0][4*q+3] += a0 * w.w;
            acc[1][4*q+0] += a1 * w.x;  acc[1][4*q+1] += a1 * w.y;
            acc[1][4*q+2] += a1 * w.z;  acc[1][4*q+3] += a1 * w.w;
            acc[2][4*q+0] += a2 * w.x;  acc[2][4*q+1] += a2 * w.y;
            acc[2][4*q+2] += a2 * w.z;  acc[2][4*q+3] += a2 * w.w;
            acc[3][4*q+0] += a3 * w.x;  acc[3][4*q+1] += a3 * w.y;
            acc[3][4*q+2] += a3 * w.z;  acc[3][4*q+3] += a3 * w.w;
        }
    }

    if (TM) {
        float tmv[NT];
#pragma unroll
        for (int oo = 0; oo < NT; ++oo) tmv[oo] = 0.f;
#pragma unroll
        for (int mi = 0; mi < 4; ++mi) {
            bool pres = mask[g0 + mi * 256] != 0;
#pragma unroll
            for (int oo = 0; oo < NT; ++oo) {
                float v = pres ? fmaxf(acc[mi][oo], 0.f) : 0.f;
                tmv[oo] = fmaxf(tmv[oo], v);
            }
        }
        int b = g0 >> 12;
        int lane = tid & 63;
#pragma unroll
        for (int oo = 0; oo < NT; ++oo) {
            unsigned r = wave_red_umax(__float_as_uint(tmv[oo]));
            if (lane == 63)
                atomicMax(&tmax[(b << 8) + o0 + oo], r);
        }
        return;
    }

#pragma unroll
    for (int mi = 0; mi < 4; ++mi) {
        int g = g0 + mi * 256;
#pragma unroll
        for (int oo = 0; oo < NT; ++oo) {
            float v = acc[mi][oo];
            if (RELU) v = fmaxf(v, 0.f);
            if (PM) out[(size_t)g * N + o0 + oo] = v;
            else    out[(size_t)(o0 + oo) * NPTS + g] = v;
        }
    }
}

// ---------------- h = relu((x @ inT) @ w1), head1 fused as prologue ----------------
__global__ __launch_bounds__(256) void l_h_kernel(const float* __restrict__ x,
                                                  const float* __restrict__ t1max,
                                                  const float* __restrict__ f1,   // 256x128
                                                  const float* __restrict__ f2,   // 128x36
                                                  const float* __restrict__ w1,   // 6x64
                                                  float* __restrict__ out_inT,    // (4,6,6)
                                                  float* __restrict__ hw)
{
    int blk = blockIdx.x, t = threadIdx.x;
    int b = blk >> 4;
    __shared__ float tv[256], u[128], sT[36];
    tv[t] = t1max[(size_t)b*256 + t];
    __syncthreads();
    if (t < 128) {
        float acc = 0.f;
        for (int k = 0; k < 256; ++k) acc += tv[k] * f1[(size_t)k*128 + t];
        u[t] = fmaxf(acc, 0.f);
    }
    __syncthreads();
    if (t < 36) {
        float acc = 0.f;
        for (int k = 0; k < 128; ++k) acc += u[k] * f2[(size_t)k*36 + t];
        if (t / 6 == t % 6) acc += 1.0f;
        sT[t] = acc;
        if ((blk & 15) == 0) out_inT[b*36 + t] = acc;
    }
    __syncthreads();

    int g = blk * 256 + t;
    float v[6];
#pragma unroll
    for (int c = 0; c < 6; ++c) v[c] = x[(size_t)g * 6 + c];
    float tt[6];
#pragma unroll
    for (int o = 0; o < 6; ++o) {
        float acc = 0.f;
#pragma unroll
        for (int c = 0; c < 6; ++c) acc += v[c] * sT[c*6 + o];
        tt[o] = acc;
    }
#pragma unroll 8
    for (int j = 0; j < 64; ++j) {
        float acc = 0.f;
#pragma unroll
        for (int o = 0; o < 6; ++o) acc += tt[o] * w1[o*64 + j];
        hw[(size_t)j * NPTS + g] = fmaxf(acc, 0.f);
    }
}

// ---------------- tnet2 head ----------------
__global__ __launch_bounds__(256) void head2_kernel(const float* __restrict__ t2,
                                                    const float* __restrict__ f1,  // 256x128
                                                    const float* __restrict__ f2,  // 128x4096
                                                    float* __restrict__ outT, float* __restrict__ wsT)
{
    int b = blockIdx.x, t = threadIdx.x;
    __shared__ float tv[256], u[128];
    tv[t] = t2[(size_t)b*256 + t];
    __syncthreads();
    if (t < 128) {
        float acc = 0.f;
        for (int k = 0; k < 256; ++k) acc += tv[k] * f1[(size_t)k*128 + t];
        u[t] = fmaxf(acc, 0.f);
    }
    __syncthreads();
    int j = blockIdx.y * 256 + t;
    float acc = 0.f;
#pragma unroll 8
    for (int k = 0; k < 128; ++k) acc += u[k] * f2[(size_t)k*4096 + j];
    if (j / 64 == j % 64) acc += 1.0f;
    outT[(size_t)b*4096 + j] = acc;
    wsT[(size_t)b*4096 + j]  = acc;
}

// ---------------- feats: grouped gather-max + transpose ----------------
__global__ __launch_bounds__(256) void feats_kernel(const float* __restrict__ fin,   // [16384][256] pm
                                                    const int* __restrict__ gidx,
                                                    float* __restrict__ out)         // (B,256,1024)
{
    int bid = blockIdx.x;            // b*1024 + c
    int b = bid >> 10, c = bid & 1023;
    int o = threadIdx.x;
    __shared__ int sid[NSAMP];
    if (o < NSAMP) sid[o] = gidx[(size_t)bid * NSAMP + o];
    __syncthreads();
    const float* fb = fin + (size_t)b * Np * 256;
    float m = -1e30f;
    for (int s = 0; s < NSAMP; ++s)
        m = fmaxf(m, fb[(size_t)sid[s] * 256 + o]);
    out[((size_t)b*256 + o)*NC + c] = m;
}

// ---------------- launch ----------------
extern "C" void kernel_launch(void* const* d_in, const int* in_sizes, int n_in,
                              void* d_out, int out_size, void* d_ws, size_t ws_size,
                              hipStream_t stream)
{
    const float* x      = (const float*)d_in[0];
    const float* points = (const float*)d_in[1];
    const float* t1_w1  = (const float*)d_in[2];
    const float* t1_w2  = (const float*)d_in[3];
    const float* t1_w3  = (const float*)d_in[4];
    const float* t1_f1  = (const float*)d_in[5];
    const float* t1_f2  = (const float*)d_in[6];
    const float* t2_w1  = (const float*)d_in[7];
    const float* t2_w2  = (const float*)d_in[8];
    const float* t2_w3  = (const float*)d_in[9];
    const float* t2_f1  = (const float*)d_in[10];
    const float* t2_f2  = (const float*)d_in[11];
    const float* w1     = (const float*)d_in[12];
    const float* w2     = (const float*)d_in[13];
    const float* w3     = (const float*)d_in[14];

    float* out = (float*)d_out;
    float* out_cent  = out;                 // (4,1024,3)
    float* out_gxyz  = out + 12288;         // (4,3,1024,64)
    float* out_feats = out + 798720;        // (4,256,1024)
    float* out_inT   = out + 1847296;       // (4,6,6)
    float* out_feT   = out + 1847440;       // (4,64,64)

    char* ws = (char*)d_ws;
    int*      gidx  = (int*)(ws + OFF_GIDX);
    int*      mask  = (int*)(ws + OFF_MASK);
    float*    t1max = (float*)(ws + OFF_T1);
    unsigned* t2max = (unsigned*)(ws + OFF_T2);
    float*    wsFeT = (float*)(ws + OFF_FET);
    float*    hw    = (float*)(ws + OFF_HW);
    float*    buf64 = (float*)(ws + OFF_BUF64);
    float*    buf128= (float*)(ws + OFF_BUF128);
    float*    fin   = (float*)(ws + OFF_FINAL);   // l3pre (cm) then final (pm)

    // zero mask + t1max + t2max (contiguous)
    (void)hipMemsetAsync(ws + OFF_MASK, 0, ZERO_BYTES, stream);

    // mega: fps (4 blocks) + fused t1 trunk (256 blocks) -> l3pre
    mega_kernel<<<Bb + 256, 256, 0, stream>>>(points, out_cent, x, fin, t1_w1, t1_w2, t1_w3);
    ballq_kernel<<<(Bb*NC)/4, 256, 0, stream>>>(points, out_cent, gidx, mask, out_gxyz);
    // t1 masked max (reads l3pre channel-major)
    maxmask_kernel<<<Bb*256, 256, 0, stream>>>(fin, mask, t1max);
    // h = relu((x @ inT) @ w1), head1 fused
    l_h_kernel<<<NPTS/256, 256, 0, stream>>>(x, t1max, t1_f1, t1_f2, w1, out_inT, hw);
    // tnet2 trunk (layer3 fused with masked max)
    layer2_k<64, 64, 16, true,  false, false, false><<<dim3(16, 4), 256, 0, stream>>>(hw,    t2_w1, buf64,  nullptr, nullptr);
    layer2_k<64, 128,16, true,  false, false, false><<<dim3(16, 8), 256, 0, stream>>>(buf64, t2_w2, buf128, nullptr, nullptr);
    layer2_k<128,256,16, false, false, false, true ><<<dim3(16,16), 256, 0, stream>>>(buf128,t2_w3, nullptr, mask, t2max);
    head2_kernel<<<dim3(Bb,16), 256, 0, stream>>>((const float*)t2max, t2_f1, t2_f2, out_feT, wsFeT);
    // hf = h @ feT (per-batch weights)
    layer2_k<64, 64, 16, false, false, true,  false><<<dim3(16, 4), 256, 0, stream>>>(hw,    wsFeT, buf64,  nullptr, nullptr);
    // c1 = relu(hf @ w2)
    layer2_k<64, 128,16, true,  false, false, false><<<dim3(16, 8), 256, 0, stream>>>(buf64, w2,    buf128, nullptr, nullptr);
    // final = relu(c1 @ w3), point-major
    layer2_k<128,256,16, true,  true,  false, false><<<dim3(16,16), 256, 0, stream>>>(buf128,w3,    fin,    nullptr, nullptr);
    feats_kernel<<<Bb*NC, 256, 0, stream>>>(fin, gidx, out_feats);

    (void)in_sizes; (void)n_in; (void)out_size; (void)ws_size;
}